// Round 5
// baseline (325.278 us; speedup 1.0000x reference)
//
#include <hip/hip_runtime.h>
#include <hip/hip_cooperative_groups.h>
#include <hip/hip_bf16.h>
#include <math.h>

namespace cg = cooperative_groups;

// Problem constants (B=8, N=1025, D=64 per reference setup_inputs)
#define NN 1025
#define DD 64
#define T_ROWS 8192                       // 8 * 1024
#define C_EXP 28.85390081777927f          // 20 * log2(e)
#define EXP_NEG20 2.0611536224385583e-9f  // e^-20

typedef _Float16 h8 __attribute__((ext_vector_type(8)));
typedef float f4 __attribute__((ext_vector_type(4)));

// ws layout (bytes):
//   qh   : _Float16[8192*64] @ 0         = qhat * C_EXP
//   kh   : _Float16[8192*64] @ 0x100000  = khat
//   diag : float[8192]       @ 0x200000  = 20*dot(qhat_i, khat_i)
//   scale: float[8192]                   = valid_j ? e^-20 : 0
//   s    : float[8192]                   = sum_j e^{logit_ij - 20}
#define OFF_QH   0
#define OFF_KH   (1 << 20)
#define OFF_DIAG (2 << 20)

// ---------------------------------------------------------------------------
// Fused cooperative kernel: prep -> grid.sync -> logits -> grid.sync -> loss.
// Grid MUST be 1024 blocks x 256 threads (4 blocks/CU co-resident).
// ---------------------------------------------------------------------------
__global__ __launch_bounds__(256, 4) void fused_kernel(
    const float* __restrict__ outE, const float* __restrict__ tgtE,
    const int* __restrict__ mask, char* wsb, float* out)
{
    cg::grid_group grid = cg::this_grid();

    _Float16* qh = (_Float16*)(wsb + OFF_QH);
    _Float16* kh = (_Float16*)(wsb + OFF_KH);
    float* diag  = (float*)(wsb + OFF_DIAG);
    float* scale = diag + T_ROWS;
    float* s     = scale + T_ROWS;

    int tid  = threadIdx.x;
    int wid  = tid >> 6;
    int lane = tid & 63;

    // ---- Phase 1: normalize, stage f16 (Q pre-scaled), diag, scale; zero s.
    {
        int wgid = blockIdx.x * 4 + wid;   // 4096 waves, 2 rows each
        #pragma unroll
        for (int rr = 0; rr < 2; ++rr) {
            int t = wgid * 2 + rr;
            int b = t >> 10, n = t & 1023;
            float qv = outE[(size_t)(b * NN + n) * DD + lane];
            float kv = tgtE[(size_t)(b * NN + n + 1) * DD + lane];
            float qs = qv * qv, ks = kv * kv;
            #pragma unroll
            for (int m = 32; m; m >>= 1) {
                qs += __shfl_xor(qs, m, 64);
                ks += __shfl_xor(ks, m, 64);
            }
            float qn  = qv * (1.0f / fmaxf(sqrtf(qs), 1e-12f));
            float knv = kv * (1.0f / fmaxf(sqrtf(ks), 1e-12f));
            qh[(size_t)t * DD + lane] = (_Float16)(qn * C_EXP);
            kh[(size_t)t * DD + lane] = (_Float16)knv;
            float dt = qn * knv;
            #pragma unroll
            for (int m = 32; m; m >>= 1) dt += __shfl_xor(dt, m, 64);
            if (lane == 0) {
                diag[t]  = 20.0f * dt;
                scale[t] = mask[b * NN + n + 1] ? EXP_NEG20 : 0.0f;
            }
        }
        if (tid < 8) s[blockIdx.x * 8 + tid] = 0.0f;   // zero accumulators
    }

    grid.sync();

    // ---- Phase 2: s[i] += sum_j exp2(dot_scaled_ij) * scale_j via f16 MFMA.
    // Block = (ib, jc); wave owns a 64-row i-strip, loops 16 j-tiles of 16.
    {
        int ib = blockIdx.x >> 5;   // 32 i-blocks of 256 rows
        int jc = blockIdx.x & 31;   // 32 j-chunks of 256 cols
        int i0 = ib * 256 + wid * 64;
        int r16 = lane & 15;        // A-row / B-col within tile
        int ko  = (lane >> 4) * 8;  // k offset within K=32 chunk

        h8 qf[4][2];
        #pragma unroll
        for (int m = 0; m < 4; ++m)
            #pragma unroll
            for (int kk = 0; kk < 2; ++kk)
                qf[m][kk] = *(const h8*)(qh + (size_t)(i0 + m * 16 + r16) * DD + kk * 32 + ko);

        float acc[4][4];
        #pragma unroll
        for (int m = 0; m < 4; ++m)
            #pragma unroll
            for (int r = 0; r < 4; ++r) acc[m][r] = 0.0f;

        int j0 = jc * 256;
        #pragma unroll 2
        for (int jt = 0; jt < 16; ++jt, j0 += 16) {
            float sc = scale[j0 + r16];
            const _Float16* kr = kh + (size_t)(j0 + r16) * DD + ko;
            h8 kf0 = *(const h8*)(kr);
            h8 kf1 = *(const h8*)(kr + 32);
            #pragma unroll
            for (int m = 0; m < 4; ++m) {
                f4 c = {0.f, 0.f, 0.f, 0.f};
                c = __builtin_amdgcn_mfma_f32_16x16x32_f16(qf[m][0], kf0, c, 0, 0, 0);
                c = __builtin_amdgcn_mfma_f32_16x16x32_f16(qf[m][1], kf1, c, 0, 0, 0);
                #pragma unroll
                for (int r = 0; r < 4; ++r)
                    acc[m][r] += __builtin_amdgcn_exp2f(c[r]) * sc;
            }
        }

        // Reduce across the 16 col-lanes (same output row), then atomics.
        #pragma unroll
        for (int msk = 1; msk < 16; msk <<= 1)
            #pragma unroll
            for (int m = 0; m < 4; ++m)
                #pragma unroll
                for (int r = 0; r < 4; ++r)
                    acc[m][r] += __shfl_xor(acc[m][r], msk, 64);

        if (r16 == 0) {
            int rbase = i0 + (lane >> 4) * 4;
            #pragma unroll
            for (int m = 0; m < 4; ++m)
                #pragma unroll
                for (int r = 0; r < 4; ++r)
                    atomicAdd(&s[rbase + m * 16 + r], acc[m][r]);
        }
    }

    grid.sync();

    // ---- Phase 3: block 0 reduces the loss and writes d_out.
    if (blockIdx.x == 0) {
        float num = 0.f, den = 0.f;
        #pragma unroll
        for (int r = 0; r < 32; ++r) {
            int t = tid + 256 * r;
            if (scale[t] != 0.0f) {
                num += diag[t] - 20.0f - logf(s[t]);
                den += 1.0f;
            }
        }
        #pragma unroll
        for (int m = 32; m; m >>= 1) {
            num += __shfl_xor(num, m, 64);
            den += __shfl_xor(den, m, 64);
        }
        __shared__ float sn[4], sd[4];
        if (lane == 0) { sn[wid] = num; sd[wid] = den; }
        __syncthreads();
        if (tid == 0)
            out[0] = -(sn[0] + sn[1] + sn[2] + sn[3]) /
                      (sd[0] + sd[1] + sd[2] + sd[3]);
    }
}

// ---------------------------------------------------------------------------
// Fallback path (separate kernels) in case cooperative launch is rejected.
// ---------------------------------------------------------------------------
__global__ __launch_bounds__(256) void prep_kernel(
    const float* __restrict__ outE, const float* __restrict__ tgtE,
    const int* __restrict__ mask, char* wsb)
{
    _Float16* qh = (_Float16*)(wsb + OFF_QH);
    _Float16* kh = (_Float16*)(wsb + OFF_KH);
    float* diag  = (float*)(wsb + OFF_DIAG);
    float* scale = diag + T_ROWS;
    float* s     = scale + T_ROWS;

    int wid  = threadIdx.x >> 6;
    int lane = threadIdx.x & 63;
    int t = blockIdx.x * 4 + wid;
    int b = t >> 10, n = t & 1023;
    float qv = outE[(size_t)(b * NN + n) * DD + lane];
    float kv = tgtE[(size_t)(b * NN + n + 1) * DD + lane];
    float qs = qv * qv, ks = kv * kv;
    #pragma unroll
    for (int m = 32; m; m >>= 1) {
        qs += __shfl_xor(qs, m, 64);
        ks += __shfl_xor(ks, m, 64);
    }
    float qn  = qv * (1.0f / fmaxf(sqrtf(qs), 1e-12f));
    float knv = kv * (1.0f / fmaxf(sqrtf(ks), 1e-12f));
    qh[(size_t)t * DD + lane] = (_Float16)(qn * C_EXP);
    kh[(size_t)t * DD + lane] = (_Float16)knv;
    float dt = qn * knv;
    #pragma unroll
    for (int m = 32; m; m >>= 1) dt += __shfl_xor(dt, m, 64);
    if (lane == 0) {
        diag[t]  = 20.0f * dt;
        scale[t] = mask[b * NN + n + 1] ? EXP_NEG20 : 0.0f;
        s[t]     = 0.0f;
    }
}

__global__ __launch_bounds__(256) void logits_kernel(char* wsb)
{
    const _Float16* qh = (const _Float16*)(wsb + OFF_QH);
    const _Float16* kh = (const _Float16*)(wsb + OFF_KH);
    const float* diag_ = (const float*)(wsb + OFF_DIAG);
    const float* scale = diag_ + T_ROWS;
    float* s = (float*)(wsb + OFF_DIAG) + 2 * T_ROWS;

    int ib = blockIdx.x >> 5;
    int jc = blockIdx.x & 31;
    int wid  = threadIdx.x >> 6;
    int lane = threadIdx.x & 63;
    int i0 = ib * 256 + wid * 64;
    int r16 = lane & 15;
    int ko  = (lane >> 4) * 8;

    h8 qf[4][2];
    #pragma unroll
    for (int m = 0; m < 4; ++m)
        #pragma unroll
        for (int kk = 0; kk < 2; ++kk)
            qf[m][kk] = *(const h8*)(qh + (size_t)(i0 + m * 16 + r16) * DD + kk * 32 + ko);

    float acc[4][4];
    #pragma unroll
    for (int m = 0; m < 4; ++m)
        #pragma unroll
        for (int r = 0; r < 4; ++r) acc[m][r] = 0.0f;

    int j0 = jc * 256;
    #pragma unroll 2
    for (int jt = 0; jt < 16; ++jt, j0 += 16) {
        float sc = scale[j0 + r16];
        const _Float16* kr = kh + (size_t)(j0 + r16) * DD + ko;
        h8 kf0 = *(const h8*)(kr);
        h8 kf1 = *(const h8*)(kr + 32);
        #pragma unroll
        for (int m = 0; m < 4; ++m) {
            f4 c = {0.f, 0.f, 0.f, 0.f};
            c = __builtin_amdgcn_mfma_f32_16x16x32_f16(qf[m][0], kf0, c, 0, 0, 0);
            c = __builtin_amdgcn_mfma_f32_16x16x32_f16(qf[m][1], kf1, c, 0, 0, 0);
            #pragma unroll
            for (int r = 0; r < 4; ++r)
                acc[m][r] += __builtin_amdgcn_exp2f(c[r]) * sc;
        }
    }

    #pragma unroll
    for (int msk = 1; msk < 16; msk <<= 1)
        #pragma unroll
        for (int m = 0; m < 4; ++m)
            #pragma unroll
            for (int r = 0; r < 4; ++r)
                acc[m][r] += __shfl_xor(acc[m][r], msk, 64);

    if (r16 == 0) {
        int rbase = i0 + (lane >> 4) * 4;
        #pragma unroll
        for (int m = 0; m < 4; ++m)
            #pragma unroll
            for (int r = 0; r < 4; ++r)
                atomicAdd(&s[rbase + m * 16 + r], acc[m][r]);
    }
}

__global__ __launch_bounds__(256) void loss_single(char* wsb, float* out)
{
    const float* diag  = (const float*)(wsb + OFF_DIAG);
    const float* scale = diag + T_ROWS;
    const float* s     = scale + T_ROWS;
    int tid = threadIdx.x;
    int wid = tid >> 6, lane = tid & 63;
    float num = 0.f, den = 0.f;
    #pragma unroll
    for (int r = 0; r < 32; ++r) {
        int t = tid + 256 * r;
        if (scale[t] != 0.0f) {
            num += diag[t] - 20.0f - logf(s[t]);
            den += 1.0f;
        }
    }
    #pragma unroll
    for (int m = 32; m; m >>= 1) {
        num += __shfl_xor(num, m, 64);
        den += __shfl_xor(den, m, 64);
    }
    __shared__ float sn[4], sd[4];
    if (lane == 0) { sn[wid] = num; sd[wid] = den; }
    __syncthreads();
    if (tid == 0)
        out[0] = -(sn[0] + sn[1] + sn[2] + sn[3]) /
                  (sd[0] + sd[1] + sd[2] + sd[3]);
}

extern "C" void kernel_launch(void* const* d_in, const int* in_sizes, int n_in,
                              void* d_out, int out_size, void* d_ws, size_t ws_size,
                              hipStream_t stream) {
    const float* outE = (const float*)d_in[0];
    const float* tgtE = (const float*)d_in[1];
    const int*   mask = (const int*)d_in[2];
    char* wsb = (char*)d_ws;
    float* out = (float*)d_out;

    void* args[] = {(void*)&outE, (void*)&tgtE, (void*)&mask, (void*)&wsb, (void*)&out};
    hipError_t rc = hipLaunchCooperativeKernel((const void*)fused_kernel,
                                               dim3(1024), dim3(256), args, 0, stream);
    if (rc != hipSuccess) {
        // Fallback: separate-kernel pipeline (no cooperative features).
        prep_kernel<<<T_ROWS / 4, 256, 0, stream>>>(outE, tgtE, mask, wsb);
        logits_kernel<<<32 * 32, 256, 0, stream>>>(wsb);
        loss_single<<<1, 256, 0, stream>>>(wsb, out);
    }
}

// Round 6
// 115.745 us; speedup vs baseline: 2.8103x; 2.8103x over previous
//
#include <hip/hip_runtime.h>
#include <hip/hip_bf16.h>
#include <math.h>

// Problem constants (B=8, N=1025, D=64 per reference setup_inputs)
#define NN 1025
#define DD 64
#define T_ROWS 8192                       // 8 * 1024
#define C_EXP 28.85390081777927f          // 20 * log2(e)
#define EXP_NEG20 2.0611536224385583e-9f  // e^-20
#define LOGITS_BLOCKS 1024

typedef _Float16 h8 __attribute__((ext_vector_type(8)));
typedef float f4 __attribute__((ext_vector_type(4)));

// ws layout (bytes):
//   qh   : _Float16[8192*64] @ 0         = qhat * C_EXP
//   kh   : _Float16[8192*64] @ 0x100000  = khat
//   diag : float[8192]       @ 0x200000  = 20*dot(qhat_i, khat_i)
//   scale: float[8192]                   = valid_j ? e^-20 : 0
//   s    : float[8192]                   = sum_j e^{logit_ij - 20}
//   cnt  : unsigned                      = finished-block counter
#define OFF_QH   0
#define OFF_KH   (1 << 20)
#define OFF_DIAG (2 << 20)

// ---------------------------------------------------------------------------
// Prep: L2-normalize, stage f16 (Q pre-scaled by 20*log2e), exact fp32 diag,
// multiplicative mask, zero s + counter. One wave per row.
// ---------------------------------------------------------------------------
__global__ __launch_bounds__(256) void prep_kernel(
    const float* __restrict__ outE, const float* __restrict__ tgtE,
    const int* __restrict__ mask, char* wsb)
{
    _Float16* qh = (_Float16*)(wsb + OFF_QH);
    _Float16* kh = (_Float16*)(wsb + OFF_KH);
    float* diag  = (float*)(wsb + OFF_DIAG);
    float* scale = diag + T_ROWS;
    float* s     = scale + T_ROWS;
    unsigned* cnt = (unsigned*)(s + T_ROWS);

    int wid  = threadIdx.x >> 6;
    int lane = threadIdx.x & 63;
    int t = blockIdx.x * 4 + wid;
    int b = t >> 10, n = t & 1023;
    float qv = outE[(size_t)(b * NN + n) * DD + lane];
    float kv = tgtE[(size_t)(b * NN + n + 1) * DD + lane];
    float qs = qv * qv, ks = kv * kv;
    #pragma unroll
    for (int m = 32; m; m >>= 1) {
        qs += __shfl_xor(qs, m, 64);
        ks += __shfl_xor(ks, m, 64);
    }
    float qn  = qv * (1.0f / fmaxf(sqrtf(qs), 1e-12f));
    float knv = kv * (1.0f / fmaxf(sqrtf(ks), 1e-12f));
    qh[(size_t)t * DD + lane] = (_Float16)(qn * C_EXP);
    kh[(size_t)t * DD + lane] = (_Float16)knv;
    float dt = qn * knv;
    #pragma unroll
    for (int m = 32; m; m >>= 1) dt += __shfl_xor(dt, m, 64);
    if (lane == 0) {
        diag[t]  = 20.0f * dt;
        scale[t] = mask[b * NN + n + 1] ? EXP_NEG20 : 0.0f;
        s[t]     = 0.0f;
        if (t == 0) *cnt = 0u;
    }
}

// ---------------------------------------------------------------------------
// Logits + fused loss: s[i] += sum_j exp2(dot_scaled_ij)*scale_j via f16 MFMA
// (m89-verified 16x16x32 layout); the LAST block to finish (device-scope
// counter) reduces the loss and writes d_out. No grid-wide sync, no extra
// kernel launches.
// ---------------------------------------------------------------------------
__global__ __launch_bounds__(256) void logits_loss_kernel(char* wsb, float* out)
{
    const _Float16* qh = (const _Float16*)(wsb + OFF_QH);
    const _Float16* kh = (const _Float16*)(wsb + OFF_KH);
    const float* diag  = (const float*)(wsb + OFF_DIAG);
    const float* scale = diag + T_ROWS;
    float* s = (float*)(wsb + OFF_DIAG) + 2 * T_ROWS;
    unsigned* cnt = (unsigned*)(s + T_ROWS);

    int tid  = threadIdx.x;
    int ib = blockIdx.x >> 5;   // 32 i-blocks of 256 rows
    int jc = blockIdx.x & 31;   // 32 j-chunks of 256 cols
    int wid  = tid >> 6;
    int lane = tid & 63;
    int i0 = ib * 256 + wid * 64;
    int r16 = lane & 15;        // A-row / B-col within tile
    int ko  = (lane >> 4) * 8;  // k offset within K=32 chunk

    h8 qf[4][2];
    #pragma unroll
    for (int m = 0; m < 4; ++m)
        #pragma unroll
        for (int kk = 0; kk < 2; ++kk)
            qf[m][kk] = *(const h8*)(qh + (size_t)(i0 + m * 16 + r16) * DD + kk * 32 + ko);

    float acc[4][4];
    #pragma unroll
    for (int m = 0; m < 4; ++m)
        #pragma unroll
        for (int r = 0; r < 4; ++r) acc[m][r] = 0.0f;

    int j0 = jc * 256;
    #pragma unroll 2
    for (int jt = 0; jt < 16; ++jt, j0 += 16) {
        float sc = scale[j0 + r16];
        const _Float16* kr = kh + (size_t)(j0 + r16) * DD + ko;
        h8 kf0 = *(const h8*)(kr);
        h8 kf1 = *(const h8*)(kr + 32);
        #pragma unroll
        for (int m = 0; m < 4; ++m) {
            f4 c = {0.f, 0.f, 0.f, 0.f};
            c = __builtin_amdgcn_mfma_f32_16x16x32_f16(qf[m][0], kf0, c, 0, 0, 0);
            c = __builtin_amdgcn_mfma_f32_16x16x32_f16(qf[m][1], kf1, c, 0, 0, 0);
            #pragma unroll
            for (int r = 0; r < 4; ++r)
                acc[m][r] += __builtin_amdgcn_exp2f(c[r]) * sc;
        }
    }

    // Reduce across the 16 col-lanes (same output row), then device atomics.
    #pragma unroll
    for (int msk = 1; msk < 16; msk <<= 1)
        #pragma unroll
        for (int m = 0; m < 4; ++m)
            #pragma unroll
            for (int r = 0; r < 4; ++r)
                acc[m][r] += __shfl_xor(acc[m][r], msk, 64);

    if (r16 == 0) {
        int rbase = i0 + (lane >> 4) * 4;
        #pragma unroll
        for (int m = 0; m < 4; ++m)
            #pragma unroll
            for (int r = 0; r < 4; ++r)
                atomicAdd(&s[rbase + m * 16 + r], acc[m][r]);
    }

    // ---- Last-block-done loss reduction (no grid sync).
    // __syncthreads() drains this block's vmcnt -> its s-atomics are at L2
    // (device-coherent) before thread 0 bumps the counter.
    __syncthreads();
    __shared__ unsigned is_last;
    if (tid == 0) {
        __threadfence();
        is_last = (atomicAdd(cnt, 1u) == LOGITS_BLOCKS - 1) ? 1u : 0u;
    }
    __syncthreads();
    if (is_last) {
        __threadfence();
        float num = 0.f, den = 0.f;
        #pragma unroll
        for (int r = 0; r < 32; ++r) {
            int t = tid + 256 * r;
            if (scale[t] != 0.0f) {
                float sv = __hip_atomic_load(&s[t], __ATOMIC_RELAXED,
                                             __HIP_MEMORY_SCOPE_AGENT);
                num += diag[t] - 20.0f - logf(sv);
                den += 1.0f;
            }
        }
        #pragma unroll
        for (int m = 32; m; m >>= 1) {
            num += __shfl_xor(num, m, 64);
            den += __shfl_xor(den, m, 64);
        }
        __shared__ float sn[4], sd[4];
        if (lane == 0) { sn[wid] = num; sd[wid] = den; }
        __syncthreads();
        if (tid == 0)
            out[0] = -(sn[0] + sn[1] + sn[2] + sn[3]) /
                      (sd[0] + sd[1] + sd[2] + sd[3]);
    }
}

extern "C" void kernel_launch(void* const* d_in, const int* in_sizes, int n_in,
                              void* d_out, int out_size, void* d_ws, size_t ws_size,
                              hipStream_t stream) {
    const float* outE = (const float*)d_in[0];
    const float* tgtE = (const float*)d_in[1];
    const int*   mask = (const int*)d_in[2];
    char* wsb = (char*)d_ws;
    float* out = (float*)d_out;

    prep_kernel<<<T_ROWS / 4, 256, 0, stream>>>(outE, tgtE, mask, wsb);
    logits_loss_kernel<<<LOGITS_BLOCKS, 256, 0, stream>>>(wsb, out);
}

// Round 8
// 103.467 us; speedup vs baseline: 3.1438x; 1.1187x over previous
//
#include <hip/hip_runtime.h>
#include <hip/hip_bf16.h>
#include <math.h>

// Problem constants (B=8, N=1025, D=64 per reference setup_inputs)
#define NN 1025
#define DD 64
#define T_ROWS 8192                       // 8 * 1024
#define C_EXP 28.85390081777927f          // 20 * log2(e)
#define EXP_NEG20 2.0611536224385583e-9f  // e^-20
#define LOGITS_BLOCKS 1024

typedef _Float16 h8 __attribute__((ext_vector_type(8)));
typedef float f4 __attribute__((ext_vector_type(4)));

// ws layout (bytes):
//   qh   : _Float16[8192*64] @ 0         = qhat * C_EXP
//   kh   : _Float16[8192*64] @ 0x100000  = khat
//   diag : float[8192]       @ 0x200000  = 20*dot(qhat_i, khat_i)
//   scale: float[8192]                   = valid_j ? e^-20 : 0
//   s    : float[8192]                   = sum_j e^{logit_ij - 20}
//   cnt  : unsigned                      = finished-block counter
#define OFF_QH   0
#define OFF_KH   (1 << 20)
#define OFF_DIAG (2 << 20)

// ---------------------------------------------------------------------------
// Prep: L2-normalize, stage f16 (Q pre-scaled by 20*log2e), exact fp32 diag,
// multiplicative mask, zero s + counter. One wave per row.
// ---------------------------------------------------------------------------
__global__ __launch_bounds__(256) void prep_kernel(
    const float* __restrict__ outE, const float* __restrict__ tgtE,
    const int* __restrict__ mask, char* wsb)
{
    _Float16* qh = (_Float16*)(wsb + OFF_QH);
    _Float16* kh = (_Float16*)(wsb + OFF_KH);
    float* diag  = (float*)(wsb + OFF_DIAG);
    float* scale = diag + T_ROWS;
    float* s     = scale + T_ROWS;
    unsigned* cnt = (unsigned*)(s + T_ROWS);

    int wid  = threadIdx.x >> 6;
    int lane = threadIdx.x & 63;
    int t = blockIdx.x * 4 + wid;
    int b = t >> 10, n = t & 1023;
    float qv = outE[(size_t)(b * NN + n) * DD + lane];
    float kv = tgtE[(size_t)(b * NN + n + 1) * DD + lane];
    float qs = qv * qv, ks = kv * kv;
    #pragma unroll
    for (int m = 32; m; m >>= 1) {
        qs += __shfl_xor(qs, m, 64);
        ks += __shfl_xor(ks, m, 64);
    }
    float qn  = qv * (1.0f / fmaxf(sqrtf(qs), 1e-12f));
    float knv = kv * (1.0f / fmaxf(sqrtf(ks), 1e-12f));
    qh[(size_t)t * DD + lane] = (_Float16)(qn * C_EXP);
    kh[(size_t)t * DD + lane] = (_Float16)knv;
    float dt = qn * knv;
    #pragma unroll
    for (int m = 32; m; m >>= 1) dt += __shfl_xor(dt, m, 64);
    if (lane == 0) {
        diag[t]  = 20.0f * dt;
        scale[t] = mask[b * NN + n + 1] ? EXP_NEG20 : 0.0f;
        s[t]     = 0.0f;
        if (t == 0) *cnt = 0u;
    }
}

// ---------------------------------------------------------------------------
// Logits + fused loss. Block = (ib: 256 i-rows, jc: 256 j-cols), 4 waves.
// K-chunk (256 rows x 128 B) + scale staged in LDS once per block with the
// G4 XOR swizzle (byte ^= (row&7)<<4) so ds_read_b128 fragment reads are
// uniform 8-words/bank. __launch_bounds__(256,2) caps occupancy target so
// the allocator keeps qf/acc resident (round-6 failure: VGPR 40 => 4 MB of
// scratch spills, WRITE_SIZE counter).
// Last block (device-scope counter) reduces the loss and writes d_out.
// ---------------------------------------------------------------------------
__global__ __launch_bounds__(256, 2) void logits_loss_kernel(char* wsb, float* out)
{
    const _Float16* qh = (const _Float16*)(wsb + OFF_QH);
    const _Float16* kh = (const _Float16*)(wsb + OFF_KH);
    const float* diag  = (const float*)(wsb + OFF_DIAG);
    const float* scale = diag + T_ROWS;
    float* s = (float*)(wsb + OFF_DIAG) + 2 * T_ROWS;
    unsigned* cnt = (unsigned*)(s + T_ROWS);

    __shared__ __align__(16) char kbuf[32768];   // 256 rows x 128 B, swizzled
    __shared__ float sbuf[256];

    int tid  = threadIdx.x;
    int ib = blockIdx.x >> 5;   // 32 i-blocks of 256 rows
    int jc = blockIdx.x & 31;   // 32 j-chunks of 256 cols
    int wid  = tid >> 6;
    int lane = tid & 63;
    int i0 = ib * 256 + wid * 64;
    int j0base = jc * 256;
    int r16 = lane & 15;          // A-row / B-col within 16x16 tile
    int g   = lane >> 4;          // k-group 0..3
    int ko  = g * 8;              // f16 k offset within K=32 chunk

    // Q fragments (wave-private rows) — loop-invariant, must stay in VGPRs.
    h8 qf[4][2];
    #pragma unroll
    for (int m = 0; m < 4; ++m)
        #pragma unroll
        for (int kk = 0; kk < 2; ++kk)
            qf[m][kk] = *(const h8*)(qh + (size_t)(i0 + m * 16 + r16) * DD + kk * 32 + ko);

    // Stage K chunk into LDS, swizzled: LDS[o ^ ((row&7)<<4)] = G[o].
    {
        const char* ksrc = (const char*)(kh + (size_t)j0base * DD);
        #pragma unroll
        for (int is = 0; is < 8; ++is) {
            int o = is * 4096 + tid * 16;
            int f = o ^ (((o >> 7) & 7) << 4);
            *(float4*)(kbuf + f) = *(const float4*)(ksrc + o);
        }
        sbuf[tid] = scale[j0base + tid];
    }
    __syncthreads();

    float acc[4][4];
    #pragma unroll
    for (int m = 0; m < 4; ++m)
        #pragma unroll
        for (int r = 0; r < 4; ++r) acc[m][r] = 0.0f;

    #pragma unroll 4
    for (int jt = 0; jt < 16; ++jt) {
        int row = jt * 16 + r16;
        int sw  = (row & 7) << 4;
        float sc = sbuf[jt * 16 + r16];
        h8 kf0 = *(const h8*)(kbuf + row * 128 + ((g * 16) ^ sw));
        h8 kf1 = *(const h8*)(kbuf + row * 128 + ((64 + g * 16) ^ sw));
        #pragma unroll
        for (int m = 0; m < 4; ++m) {
            f4 c = {0.f, 0.f, 0.f, 0.f};
            c = __builtin_amdgcn_mfma_f32_16x16x32_f16(qf[m][0], kf0, c, 0, 0, 0);
            c = __builtin_amdgcn_mfma_f32_16x16x32_f16(qf[m][1], kf1, c, 0, 0, 0);
            #pragma unroll
            for (int r = 0; r < 4; ++r)
                acc[m][r] += __builtin_amdgcn_exp2f(c[r]) * sc;
        }
    }

    // Reduce across the 16 col-lanes (same output row), then device atomics.
    #pragma unroll
    for (int msk = 1; msk < 16; msk <<= 1)
        #pragma unroll
        for (int m = 0; m < 4; ++m)
            #pragma unroll
            for (int r = 0; r < 4; ++r)
                acc[m][r] += __shfl_xor(acc[m][r], msk, 64);

    if (r16 == 0) {
        int rbase = i0 + g * 4;
        #pragma unroll
        for (int m = 0; m < 4; ++m)
            #pragma unroll
            for (int r = 0; r < 4; ++r)
                atomicAdd(&s[rbase + m * 16 + r], acc[m][r]);
    }

    // ---- Last-block-done loss reduction (no grid sync).
    __syncthreads();
    __shared__ unsigned is_last;
    if (tid == 0) {
        __threadfence();
        is_last = (atomicAdd(cnt, 1u) == LOGITS_BLOCKS - 1) ? 1u : 0u;
    }
    __syncthreads();
    if (is_last) {
        __threadfence();
        float num = 0.f, den = 0.f;
        #pragma unroll
        for (int r = 0; r < 32; ++r) {
            int t = tid + 256 * r;
            if (scale[t] != 0.0f) {
                float sv = __hip_atomic_load(&s[t], __ATOMIC_RELAXED,
                                             __HIP_MEMORY_SCOPE_AGENT);
                num += diag[t] - 20.0f - logf(sv);
                den += 1.0f;
            }
        }
        #pragma unroll
        for (int m = 32; m; m >>= 1) {
            num += __shfl_xor(num, m, 64);
            den += __shfl_xor(den, m, 64);
        }
        __shared__ float sn[4], sd[4];
        if (lane == 0) { sn[wid] = num; sd[wid] = den; }
        __syncthreads();
        if (tid == 0)
            out[0] = -(sn[0] + sn[1] + sn[2] + sn[3]) /
                      (sd[0] + sd[1] + sd[2] + sd[3]);
    }
}

extern "C" void kernel_launch(void* const* d_in, const int* in_sizes, int n_in,
                              void* d_out, int out_size, void* d_ws, size_t ws_size,
                              hipStream_t stream) {
    const float* outE = (const float*)d_in[0];
    const float* tgtE = (const float*)d_in[1];
    const int*   mask = (const int*)d_in[2];
    char* wsb = (char*)d_ws;
    float* out = (float*)d_out;

    prep_kernel<<<T_ROWS / 4, 256, 0, stream>>>(outE, tgtE, mask, wsb);
    logits_loss_kernel<<<LOGITS_BLOCKS, 256, 0, stream>>>(wsb, out);
}